// Round 11
// baseline (167.269 us; speedup 1.0000x reference)
//
#include <hip/hip_runtime.h>

#define HD 64   // hidden dim D

typedef short  bf16x8 __attribute__((ext_vector_type(8)));
typedef float  f32x4  __attribute__((ext_vector_type(4)));

__device__ inline float bf2f(ushort u) {
    unsigned x = ((unsigned)u) << 16;
    return __builtin_bit_cast(float, x);
}
__device__ inline ushort f2bf(float f) {   // round-to-nearest-even
    unsigned u = __builtin_bit_cast(unsigned, f);
    u += 0x7fffu + ((u >> 16) & 1u);
    return (ushort)(u >> 16);
}

// ---- fused prep: zero deg | f2bf(x) | f2bf(W) ----
__global__ void prep_kernel(const float4* __restrict__ x, ushort4* __restrict__ hb, int xn4,
                            const float4* __restrict__ W, ushort4* __restrict__ Wb, int wn4,
                            int4* __restrict__ deg4, int dn4) {
    int i = blockIdx.x * blockDim.x + threadIdx.x;
    if (i < xn4) {
        float4 v = x[i];
        ushort4 o; o.x = f2bf(v.x); o.y = f2bf(v.y); o.z = f2bf(v.z); o.w = f2bf(v.w);
        hb[i] = o;
        return;
    }
    int j = i - xn4;
    if (j < wn4) {
        float4 v = W[j];
        ushort4 o; o.x = f2bf(v.x); o.y = f2bf(v.y); o.z = f2bf(v.z); o.w = f2bf(v.w);
        Wb[j] = o;
        return;
    }
    int k = j - wn4;
    if (k < dn4) deg4[k] = int4{0, 0, 0, 0};
}

// ---- degree histogram, dst-range partitioned (XCD-local atomic lines) ----
__global__ void deg_part_kernel(const int* __restrict__ dst, int* __restrict__ deg,
                                int E, int N) {
    const int g = blockIdx.x & 7;
    const int per = (N + 7) / 8;
    const int lo = g * per;
    const int hi = min(N, lo + per);
    const int nb = gridDim.x >> 3;
    const int b = blockIdx.x >> 3;
    for (int e = b * blockDim.x + threadIdx.x; e < E; e += nb * blockDim.x) {
        int d = dst[e];
        if (d >= lo && d < hi) atomicAdd(&deg[d], 1);
    }
}

// ---- per-block local exclusive scan of deg ----
__global__ __launch_bounds__(1024) void scanA_kernel(const int* __restrict__ deg,
                                                     int* __restrict__ excl,
                                                     int* __restrict__ bsum, int N) {
    const int tid = threadIdx.x, lane = tid & 63, wid = tid >> 6;
    const int i = blockIdx.x * 1024 + tid;
    int v = (i < N) ? deg[i] : 0;
    int s = v;
#pragma unroll
    for (int off = 1; off < 64; off <<= 1) {
        int t = __shfl_up(s, off, 64);
        if (lane >= off) s += t;
    }
    __shared__ int wtot[16], woff[16];
    if (lane == 63) wtot[wid] = s;
    __syncthreads();
    if (wid == 0 && lane < 16) {
        int t = wtot[lane];
        int ss = t;
#pragma unroll
        for (int off = 1; off < 16; off <<= 1) {
            int u = __shfl_up(ss, off, 64);
            if (lane >= off) ss += u;
        }
        woff[lane] = ss - t;
        if (lane == 15) bsum[blockIdx.x] = ss;
    }
    __syncthreads();
    if (i < N) excl[i] = woff[wid] + (s - v);
}

// ---- apply: scans bsum (NB<=64) in-wave per block ----
__global__ __launch_bounds__(1024) void scanC_kernel(const int* __restrict__ excl,
                                                     const int* __restrict__ bsum,
                                                     const int* __restrict__ deg,
                                                     int* __restrict__ row_start,
                                                     int* __restrict__ cursor,
                                                     float* __restrict__ inv_deg,
                                                     int N, int E, int NB) {
    __shared__ int boff_s;
    const int tid = threadIdx.x;
    if (tid < 64) {
        int lane = tid;
        int v = (lane < NB) ? bsum[lane] : 0;
        int s = v;
#pragma unroll
        for (int off = 1; off < 64; off <<= 1) {
            int t = __shfl_up(s, off, 64);
            if (lane >= off) s += t;
        }
        if (lane == (int)blockIdx.x) boff_s = s - v;
    }
    __syncthreads();
    const int boff = boff_s;
    int i = blockIdx.x * 1024 + tid;
    if (i < N) {
        int e = excl[i] + boff;
        row_start[i] = e;
        cursor[i] = e;
        int d = deg[i];
        inv_deg[i] = (d > 0) ? 1.0f / (float)d : 0.0f;
    }
    if (blockIdx.x == 0 && tid == 0) row_start[N] = E;
}

// ---- CSR fill, dst-range partitioned ----
__global__ void fill_part_kernel(const int* __restrict__ src, const int* __restrict__ dst,
                                 int* __restrict__ cursor, int* __restrict__ csr,
                                 int E, int N) {
    const int g = blockIdx.x & 7;
    const int per = (N + 7) / 8;
    const int lo = g * per;
    const int hi = min(N, lo + per);
    const int nb = gridDim.x >> 3;
    const int b = blockIdx.x >> 3;
    for (int e = b * blockDim.x + threadIdx.x; e < E; e += nb * blockDim.x) {
        int d = dst[e];
        if (d >= lo && d < hi) {
            int p = atomicAdd(&cursor[d], 1);
            csr[p] = src[e];
        }
    }
}

// ---- FUSED layer: gather-mean into A-frag registers + MFMA + relu + L2-norm ----
// 256 thr / 4 waves, NO LDS (round-5 lesson: fusion only works without the LDS
// occupancy tax). Wave owns 16 consecutive nodes. Lane (m=lane&15, kq=lane>>4)
// aggregates node base+m's neighbor mean over dims [kq*8..+7] and [32+kq*8..+7]
// (= exactly its A-frag slots for kk=2,3), while self dims load directly as
// bf16x8 frags (kk=0,1). Gather loop runs to wave-max degree with masked fmas.
// Then 16x mfma_f32_16x16x32_bf16 (layout verified rounds 9-10) + norm epilogue.
// NOT in-place safe (gathers arbitrary rows) -> ping-pong.
__global__ __launch_bounds__(256) void layer_mfma_kernel(
    const ushort* __restrict__ hb, const int* __restrict__ row_start,
    const int* __restrict__ csr, const float* __restrict__ inv_deg,
    const ushort* __restrict__ Wb, float* __restrict__ out,
    ushort* __restrict__ hb_out, int N, int E, int last) {
    const int lane = threadIdx.x & 63;
    const int w = threadIdx.x >> 6;
    const int base = blockIdx.x * 64 + w * 16;
    const int m = lane & 15;
    const int kq = lane >> 4;
    int cnode = base + m;
    if (cnode > N - 1) cnode = N - 1;        // clamp reads; stores guarded
    const int arow = cnode << 6;             // *HD

    // self fragments (kk=0,1) — issue early
    bf16x8 a0 = *(const bf16x8*)(hb + arow + kq * 8);
    bf16x8 a1 = *(const bf16x8*)(hb + arow + 32 + kq * 8);

    const int r0 = row_start[cnode];
    const int dg = row_start[cnode + 1] - r0;
    const float inv = inv_deg[cnode];

    int dgmax = dg;
#pragma unroll
    for (int off = 1; off < 64; off <<= 1)
        dgmax = max(dgmax, __shfl_xor(dgmax, off, 64));

    float accL[8] = {0.f,0.f,0.f,0.f,0.f,0.f,0.f,0.f};
    float accH[8] = {0.f,0.f,0.f,0.f,0.f,0.f,0.f,0.f};
    const int Em1 = E - 1;
    for (int j = 0; j < dgmax; j += 2) {
        int p0 = r0 + j;       if (p0 > Em1) p0 = Em1;
        int p1 = r0 + j + 1;   if (p1 > Em1) p1 = Em1;
        int s0 = csr[p0];
        int s1 = csr[p1];
        float w0 = (j < dg) ? 1.f : 0.f;
        float w1 = (j + 1 < dg) ? 1.f : 0.f;
        const ushort* q0 = hb + (s0 << 6) + kq * 8;
        const ushort* q1 = hb + (s1 << 6) + kq * 8;
        bf16x8 l0 = *(const bf16x8*)q0;
        bf16x8 h0 = *(const bf16x8*)(q0 + 32);
        bf16x8 l1 = *(const bf16x8*)q1;
        bf16x8 h1 = *(const bf16x8*)(q1 + 32);
#pragma unroll
        for (int i = 0; i < 8; ++i) {
            accL[i] = fmaf(w0, bf2f((ushort)l0[i]), accL[i]);
            accH[i] = fmaf(w0, bf2f((ushort)h0[i]), accH[i]);
        }
#pragma unroll
        for (int i = 0; i < 8; ++i) {
            accL[i] = fmaf(w1, bf2f((ushort)l1[i]), accL[i]);
            accH[i] = fmaf(w1, bf2f((ushort)h1[i]), accH[i]);
        }
    }
    // mean -> bf16 A-frags for kk=2,3 (same rounding as the old neighb store)
    bf16x8 a2, a3;
#pragma unroll
    for (int i = 0; i < 8; ++i) {
        a2[i] = (short)f2bf(accL[i] * inv);
        a3[i] = (short)f2bf(accH[i] * inv);
    }

    // MFMA: 4 K-steps x 4 N-tiles; B frags from global (L2-hit)
    f32x4 acc[4] = {{0.f,0.f,0.f,0.f},{0.f,0.f,0.f,0.f},{0.f,0.f,0.f,0.f},{0.f,0.f,0.f,0.f}};
#pragma unroll
    for (int kk = 0; kk < 4; ++kk) {
        bf16x8 a = (kk == 0) ? a0 : (kk == 1) ? a1 : (kk == 2) ? a2 : a3;
        const ushort* bp = Wb + m * 128 + kk * 32 + kq * 8;
#pragma unroll
        for (int t = 0; t < 4; ++t) {
            bf16x8 b = *(const bf16x8*)(bp + t * 16 * 128);
            acc[t] = __builtin_amdgcn_mfma_f32_16x16x32_bf16(a, b, acc[t], 0, 0, 0);
        }
    }

    // relu + per-node (C-row) L2 norm. C/D: col(out)=m, row(node)=kq*4+r.
    float sq[4] = {0.f, 0.f, 0.f, 0.f};
#pragma unroll
    for (int t = 0; t < 4; ++t)
#pragma unroll
        for (int r = 0; r < 4; ++r) {
            float v = fmaxf(acc[t][r], 0.f);
            acc[t][r] = v;
            sq[r] += v * v;
        }
#pragma unroll
    for (int off = 1; off < 16; off <<= 1)
#pragma unroll
        for (int r = 0; r < 4; ++r) sq[r] += __shfl_xor(sq[r], off, 64);

    float scl[4];
#pragma unroll
    for (int r = 0; r < 4; ++r) scl[r] = 1.f / fmaxf(sqrtf(sq[r]), 1e-12f);

    if (last) {
#pragma unroll
        for (int r = 0; r < 4; ++r) {
            int node = base + kq * 4 + r;
            if (node < N) {
#pragma unroll
                for (int t = 0; t < 4; ++t)
                    out[(long long)node * HD + t * 16 + m] = acc[t][r] * scl[r];
            }
        }
    } else {
#pragma unroll
        for (int r = 0; r < 4; ++r) {
            int node = base + kq * 4 + r;
            if (node < N) {
#pragma unroll
                for (int t = 0; t < 4; ++t)
                    hb_out[(long long)node * HD + t * 16 + m] = f2bf(acc[t][r] * scl[r]);
            }
        }
    }
}

extern "C" void kernel_launch(void* const* d_in, const int* in_sizes, int n_in,
                              void* d_out, int out_size, void* d_ws, size_t ws_size,
                              hipStream_t stream) {
    const float* x    = (const float*)d_in[0];
    const float* W    = (const float*)d_in[1];
    const int*   esrc = (const int*)d_in[2];
    const int*   edst = (const int*)d_in[3];
    float* out = (float*)d_out;

    const int N = in_sizes[0] / HD;
    const int E = in_sizes[2];
    const int DEPTH = in_sizes[1] / (HD * 2 * HD);
    const int NB = (N + 1023) / 1024;

    // ws: deg | excl | bsum | row_start | cursor | inv_deg | csr | hb0 | hb1 | Wb
    auto align256 = [](size_t v) { return (v + 255) & ~(size_t)255; };
    char* ws = (char*)d_ws;
    int*    deg       = (int*)ws;     ws += align256((size_t)(N + 8) * 4);
    int*    excl      = (int*)ws;     ws += align256((size_t)N * 4);
    int*    bsum      = (int*)ws;     ws += align256(64 * 4);
    int*    row_start = (int*)ws;     ws += align256((size_t)(N + 1) * 4);
    int*    cursor    = (int*)ws;     ws += align256((size_t)N * 4);
    float*  inv_deg   = (float*)ws;   ws += align256((size_t)N * 4);
    int*    csr       = (int*)ws;     ws += align256((size_t)E * 4);
    ushort* hb0       = (ushort*)ws;  ws += align256((size_t)N * HD * 2);
    ushort* hb1       = (ushort*)ws;  ws += align256((size_t)N * HD * 2);
    ushort* Wb        = (ushort*)ws;

    // fused prep: x->bf16, W->bf16, deg=0
    int xn4 = N * HD / 4;
    int wn4 = DEPTH * HD * 2 * HD / 4;
    int dn4 = (N + 3) / 4;
    int ptot = xn4 + wn4 + dn4;
    prep_kernel<<<(ptot + 255) / 256, 256, 0, stream>>>(
        (const float4*)x, (ushort4*)hb0, xn4,
        (const float4*)W, (ushort4*)Wb, wn4,
        (int4*)deg, dn4);

    deg_part_kernel<<<2048, 256, 0, stream>>>(edst, deg, E, N);
    scanA_kernel<<<NB, 1024, 0, stream>>>(deg, excl, bsum, N);
    scanC_kernel<<<NB, 1024, 0, stream>>>(excl, bsum, deg, row_start, cursor, inv_deg, N, E, NB);
    fill_part_kernel<<<2048, 256, 0, stream>>>(esrc, edst, cursor, csr, E, N);

    ushort* hb_cur = hb0;
    ushort* hb_nxt = hb1;
    for (int k = 0; k < DEPTH; ++k) {
        int last = (k == DEPTH - 1) ? 1 : 0;
        layer_mfma_kernel<<<(N + 63) / 64, 256, 0, stream>>>(
            hb_cur, row_start, csr, inv_deg,
            Wb + (size_t)k * HD * 2 * HD, out, hb_nxt, N, E, last);
        ushort* t = hb_cur; hb_cur = hb_nxt; hb_nxt = t;
    }
}